// Round 7
// baseline (80.352 us; speedup 1.0000x reference)
//
#include <hip/hip_runtime.h>
#include <stdint.h>

#define N_ROWS  8192
#define DIM     512            // elements = bytes (fp8)
#define BJ      256            // tile rows of z2 (j, reduction axis)
#define BI      128            // tile rows of z1 (i, output axis)
#define BK      64             // K-bytes per tile
#define NT      (DIM / BK)     // 8 K-tiles
#define NCB     32             // j-blocks (8192/256)
#define NIB     64             // i-blocks (8192/128)
#define THREADS 512
#define SCL16   0x7B7B7B7BU    // e8m0 123 = 2^-4 per operand (undoes data x16)

typedef __attribute__((ext_vector_type(16))) float f32x16;
typedef __attribute__((ext_vector_type(8)))  int   i32x8;
typedef __attribute__((ext_vector_type(4)))  int   i32x4;

#define BAR()    { asm volatile("" ::: "memory"); __builtin_amdgcn_s_barrier(); asm volatile("" ::: "memory"); }
#define WAITV(n) asm volatile("s_waitcnt vmcnt(" #n ")" ::: "memory")
#define WAITL0() asm volatile("s_waitcnt lgkmcnt(0)" ::: "memory")

#define MFMA8(a, b, c) __builtin_amdgcn_mfma_scale_f32_32x32x64_f8f6f4( \
    (a), (b), (c), 0, 0, 0, SCL16, 0, SCL16)

// manual RNE float -> OCP e4m3fn (|f| <= 16 guaranteed; no NaN/inf inputs)
__device__ __forceinline__ unsigned int f2e4m3(float f) {
    unsigned int u = __float_as_uint(f);
    unsigned int s = (u >> 24) & 0x80u;
    float a = fabsf(f);
    if (a < 0.015625f) {                     // subnormal: step 2^-9
        int q = (int)rintf(a * 512.0f);      // 0..8 (8 rolls into min-normal)
        return s | (unsigned int)q;
    }
    unsigned int mag = u & 0x7fffffffu;
    mag += 0x7FFFFu + ((mag >> 20) & 1u);    // RNE into 3-bit mantissa
    return s | ((mag >> 20) - 960u);         // (E-120)<<3 | M3
}

// async global -> LDS, 16 B per lane (wave-uniform LDS base + lane*16)
__device__ __forceinline__ void gload_lds16(const void* g, void* l) {
    __builtin_amdgcn_global_load_lds(
        (const __attribute__((address_space(1))) unsigned int*)g,
        (__attribute__((address_space(3))) unsigned int*)l,
        16, 0, 0);
}

// ---------------- Kernel 1: L2-normalize rows + cast to fp8 (x16) ----------
__global__ __launch_bounds__(256) void norm_cast_kernel(
    const float* __restrict__ z1, const float* __restrict__ z2,
    unsigned char* __restrict__ o1, unsigned char* __restrict__ o2)
{
    int row  = blockIdx.x * 4 + (threadIdx.x >> 6);
    int lane = threadIdx.x & 63;
    const float* src;
    unsigned char* dst;
    if (row < N_ROWS) { src = z1 + (size_t)row * DIM;            dst = o1 + (size_t)row * DIM; }
    else              { src = z2 + (size_t)(row - N_ROWS) * DIM; dst = o2 + (size_t)(row - N_ROWS) * DIM; }

    const float4* s4 = (const float4*)src + lane * 2;
    float4 a = s4[0], b = s4[1];
    float ss = a.x*a.x + a.y*a.y + a.z*a.z + a.w*a.w
             + b.x*b.x + b.y*b.y + b.z*b.z + b.w*b.w;
#pragma unroll
    for (int x = 1; x < 64; x <<= 1) ss += __shfl_xor(ss, x);
    float inv = 16.0f / fmaxf(sqrtf(ss), 1e-12f);   // x16 into e4m3 normal range

    uint2 o;
    o.x = f2e4m3(a.x*inv) | (f2e4m3(a.y*inv) << 8) | (f2e4m3(a.z*inv) << 16) | (f2e4m3(a.w*inv) << 24);
    o.y = f2e4m3(b.x*inv) | (f2e4m3(b.y*inv) << 8) | (f2e4m3(b.z*inv) << 16) | (f2e4m3(b.w*inv) << 24);
    *(uint2*)(dst + lane * 8) = o;
}

// ---------------- Kernel 2: fused 256x128 MX-fp8 sim GEMM ------------------
// Swapped operands: acc[jb][ib] = mfma(Jfrag, Ifrag): output ROW axis = j
// (z2 row, reduction axis, register-indexed), COL axis = i (z1 row, lane).
// 8 waves x (64 j x 64 i) output each; acc = 4 x f32x16 = 64 regs -> with
// __launch_bounds__(512,4) two blocks fit per CU (LDS 57 KB) = 4 waves/SIMD.
// LDS frag layout [frag][half][lane][16B]: every global_load_lds write and
// ds_read_b128 frag read is canonical lane-linear 16 B (conflict-free).
__global__ __launch_bounds__(THREADS, 4) void fused_sim_kernel(
    const unsigned char* __restrict__ A,    // z1 fp8 [8192][512]
    const unsigned char* __restrict__ B,    // z2 fp8 [8192][512]
    const int* __restrict__ ids,
    float* __restrict__ partial)            // [3][NCB][N_ROWS]
{
    __shared__ alignas(128) unsigned char Bs[2][BJ * BK];  // 32 KB (J = z2)
    __shared__ alignas(128) unsigned char As[2][BI * BK];  // 16 KB (I = z1)
    __shared__ int   idi[BI], idj[BJ];                     // 1.5 KB
    __shared__ float red[4][3][BI];                        // 6 KB

    const int tid  = threadIdx.x;
    const int lane = tid & 63;
    const int wid  = tid >> 6;
    const int wj   = wid >> 1;                 // 0..3  (j quarter: 64 rows)
    const int wi   = wid & 1;                  // 0..1  (i half: 64 rows)

    // XCD chunking: each XCD owns a 4-wide bx (j-block) stripe; bx fastest.
    const int flat = blockIdx.x;
    const int xcd  = flat & 7;
    const int s    = flat >> 3;                // 0..255
    const int bx   = xcd * 4 + (s & 3);        // 0..31  (j block)
    const int by   = s >> 2;                   // 0..63  (i block)
    const int brow = by * BI;                  // z1 base row
    const int bcol = bx * BJ;                  // z2 base row

    if (tid < BI)            idi[tid]       = ids[brow + tid];
    else if (tid < BI + BJ)  idj[tid - BI]  = ids[bcol + (tid - BI)];
    WAITL0();

    // stage: seg -> (f = seg>>7, h = (seg>>6)&1, ln = seg&63)
    // LDS addr = seg*16 = f*2048 + h*1024 + ln*16
    // global: row = f*32 + (ln&31), kbyte = (ln>>5)*32 + h*16
    auto stageB = [&](int buf, int k0) {
#pragma unroll
        for (int g = 0; g < 2; ++g) {
            int seg = g * 512 + tid;
            int f = seg >> 7, h = (seg >> 6) & 1, ln = seg & 63;
            int row = f * 32 + (ln & 31);
            int kb  = (ln >> 5) * 32 + h * 16;
            gload_lds16(B + (size_t)(bcol + row) * DIM + k0 + kb, &Bs[buf][seg * 16]);
        }
    };
    auto stageA = [&](int buf, int k0) {
        int seg = tid;
        int f = seg >> 7, h = (seg >> 6) & 1, ln = seg & 63;
        int row = f * 32 + (ln & 31);
        int kb  = (ln >> 5) * 32 + h * 16;
        gload_lds16(A + (size_t)(brow + row) * DIM + k0 + kb, &As[buf][seg * 16]);
    };

    // fragment reads: operand row = lane&31, k-bytes = (lane>>5)*32 + 0..31,
    // stored as two lane-linear 16 B halves.
    auto ldJ = [&](int buf, int jb) -> i32x8 {
        int f = wj * 2 + jb;
        i32x4 lo = *(const i32x4*)&Bs[buf][f * 2048 + lane * 16];
        i32x4 hi = *(const i32x4*)&Bs[buf][f * 2048 + 1024 + lane * 16];
        return __builtin_shufflevector(lo, hi, 0, 1, 2, 3, 4, 5, 6, 7);
    };
    auto ldI = [&](int buf, int ib) -> i32x8 {
        int f = wi * 2 + ib;
        i32x4 lo = *(const i32x4*)&As[buf][f * 2048 + lane * 16];
        i32x4 hi = *(const i32x4*)&As[buf][f * 2048 + 1024 + lane * 16];
        return __builtin_shufflevector(lo, hi, 0, 1, 2, 3, 4, 5, 6, 7);
    };

    f32x16 acc[2][2];
#pragma unroll
    for (int m = 0; m < 2; ++m)
#pragma unroll
        for (int n = 0; n < 2; ++n) acc[m][n] = (f32x16)0.f;

    // prologue: stage tile 0, drain, barrier
    stageB(0, 0); stageA(0, 0);
    WAITV(0);
    BAR();

#pragma unroll
    for (int t = 0; t < NT; ++t) {
        const int buf = t & 1;
        if (t + 1 < NT) { stageB(buf ^ 1, (t + 1) * BK); stageA(buf ^ 1, (t + 1) * BK); }
        i32x8 j0 = ldJ(buf, 0), j1 = ldJ(buf, 1);
        i32x8 i0 = ldI(buf, 0), i1 = ldI(buf, 1);
        __builtin_amdgcn_s_setprio(1);
        acc[0][0] = MFMA8(j0, i0, acc[0][0]);
        acc[0][1] = MFMA8(j0, i1, acc[0][1]);
        acc[1][0] = MFMA8(j1, i0, acc[1][0]);
        acc[1][1] = MFMA8(j1, i1, acc[1][1]);
        __builtin_amdgcn_s_setprio(0);
        if (t + 1 < NT) { WAITV(0); }
        BAR();
    }

    // ---- epilogue: 32x32 C/D layout: col(i)=lane&31, row(j)=(reg&3)+8*(reg>>2)+4*(lane>>5)
    const int li = lane & 31, lh = lane >> 5;
    const int rid0 = idi[wi * 64 + li];
    const int rid1 = idi[wi * 64 + 32 + li];
    float dp0 = 0.f, sp0 = 0.f, qp0 = 0.f, dp1 = 0.f, sp1 = 0.f, qp1 = 0.f;
#pragma unroll
    for (int jb = 0; jb < 2; ++jb) {
#pragma unroll
        for (int reg = 0; reg < 16; ++reg) {
            int j   = wj * 64 + jb * 32 + (reg & 3) + 8 * (reg >> 2) + 4 * lh;
            int cid = idj[j];
            float v0 = acc[jb][0][reg], v1 = acc[jb][1][reg];
            float e0 = __expf(v0 * 10.0f - 10.0f);   // exp(sim - 10)
            float e1 = __expf(v1 * 10.0f - 10.0f);
            dp0 += e0; dp1 += e1;
            sp0 += (rid0 == cid) ? e0 : 0.f;  qp0 += (rid0 == cid) ? 0.f : e0 * e0;
            sp1 += (rid1 == cid) ? e1 : 0.f;  qp1 += (rid1 == cid) ? 0.f : e1 * e1;
        }
    }
    dp0 += __shfl_xor(dp0, 32); sp0 += __shfl_xor(sp0, 32); qp0 += __shfl_xor(qp0, 32);
    dp1 += __shfl_xor(dp1, 32); sp1 += __shfl_xor(sp1, 32); qp1 += __shfl_xor(qp1, 32);
    if (lane < 32) {
        red[wj][0][wi * 64 + li]      = dp0;
        red[wj][1][wi * 64 + li]      = sp0;
        red[wj][2][wi * 64 + li]      = qp0;
        red[wj][0][wi * 64 + 32 + li] = dp1;
        red[wj][1][wi * 64 + 32 + li] = sp1;
        red[wj][2][wi * 64 + 32 + li] = qp1;
    }
    __syncthreads();
    if (tid < BI) {
#pragma unroll
        for (int s2 = 0; s2 < 3; ++s2) {
            float v = red[0][s2][tid] + red[1][s2][tid] + red[2][s2][tid] + red[3][s2][tid];
            partial[((size_t)s2 * NCB + bx) * N_ROWS + brow + tid] = v;
        }
    }
}

// ---------------- Kernel 3: per-row loss, per-block sums ----------------
__global__ __launch_bounds__(256) void reduce_kernel(
    const float* __restrict__ partial, float* __restrict__ blocksum)
{
    int row = blockIdx.x * 256 + threadIdx.x;
    float den = 0.f, sm = 0.f, sq = 0.f;
#pragma unroll 4
    for (int cb = 0; cb < NCB; ++cb) {
        den += partial[((size_t)0 * NCB + cb) * N_ROWS + row];
        sm  += partial[((size_t)1 * NCB + cb) * N_ROWS + row];
        sq  += partial[((size_t)2 * NCB + cb) * N_ROWS + row];
    }
    float num  = sm + sq / den;
    float loss = -logf(num / (den + 1e-8f) + 1e-8f);
#pragma unroll
    for (int x = 1; x < 64; x <<= 1) loss += __shfl_xor(loss, x);
    __shared__ float p[4];
    if ((threadIdx.x & 63) == 0) p[threadIdx.x >> 6] = loss;
    __syncthreads();
    if (threadIdx.x == 0) blocksum[blockIdx.x] = p[0] + p[1] + p[2] + p[3];
}

__global__ void final_kernel(const float* __restrict__ blocksum, float* __restrict__ out)
{
    float v = (threadIdx.x < 32) ? blocksum[threadIdx.x] : 0.f;
#pragma unroll
    for (int x = 1; x < 64; x <<= 1) v += __shfl_xor(v, x);
    if (threadIdx.x == 0) out[0] = v * (1.0f / (float)N_ROWS);
}

extern "C" void kernel_launch(void* const* d_in, const int* in_sizes, int n_in,
                              void* d_out, int out_size, void* d_ws, size_t ws_size,
                              hipStream_t stream) {
    const float* z1  = (const float*)d_in[0];
    const float* z2  = (const float*)d_in[1];
    const int*   ids = (const int*)d_in[2];

    char* ws = (char*)d_ws;
    unsigned char* z1q = (unsigned char*)ws;                                 // 4 MB
    unsigned char* z2q = (unsigned char*)(ws + (size_t)N_ROWS * DIM);        // 4 MB
    float* partial  = (float*)(ws + (size_t)2 * N_ROWS * DIM);               // 3 MB
    float* blocksum = partial + (size_t)3 * NCB * N_ROWS;                    // 128 B

    norm_cast_kernel<<<dim3(4096), dim3(256), 0, stream>>>(z1, z2, z1q, z2q);
    fused_sim_kernel<<<dim3(2048), dim3(THREADS), 0, stream>>>(z1q, z2q, ids, partial);
    reduce_kernel<<<dim3(32), dim3(256), 0, stream>>>(partial, blocksum);
    final_kernel<<<dim3(1), dim3(64), 0, stream>>>(blocksum, (float*)d_out);
}